// Round 1
// baseline (372.972 us; speedup 1.0000x reference)
//
#include <hip/hip_runtime.h>
#include <hip/hip_bf16.h>
#include <stdint.h>

// LSTM cell: gates = [x | h_prev] @ [W;U] + b ; B=131072, E=H=128 -> GEMM M=131072, K=256, N=512
// Strategy: 3-term bf16 split-precision MFMA (hi*hi + hi*lo + lo*hi), fp32 accumulate.

#define NB 131072
#define KDIM 256
#define NDIM 512
#define BM 64

typedef __attribute__((ext_vector_type(4))) float f32x4;
typedef __attribute__((ext_vector_type(8))) short s16x8;

__device__ __forceinline__ unsigned short f2bf(float f) {
    union { float f; unsigned int u; } v; v.f = f;
    unsigned int u = v.u;
    unsigned int r = u + 0x7FFFu + ((u >> 16) & 1u);   // round-to-nearest-even
    return (unsigned short)(r >> 16);
}
__device__ __forceinline__ float bf2f(unsigned short h) {
    union { float f; unsigned int u; } v; v.u = ((unsigned int)h) << 16;
    return v.f;
}
__device__ __forceinline__ float sigmoid_f(float x) {
    return 1.0f / (1.0f + __expf(-x));
}
__device__ __forceinline__ float tanh_f(float x) {
    float e = __expf(2.0f * x);          // inf-safe: x>>0 -> 1, x<<0 -> -1
    return 1.0f - 2.0f / (e + 1.0f);
}

// ---------------------------------------------------------------------------
// Prepass: pack W/U (fp32) into per-lane MFMA B-fragment order, bf16 hi/lo.
// Layout: frag block (kf, jg) holds B[k = kf*32 + (lane>>4)*8 + e][j = jg*16 + (lane&15)]
// stored at ushort offset ((kf*32 + jg)*64 + lane)*8 + e.
// Bmat[k][j]: j = g*128 + jj (gate order i,f,o,c); k<128 -> Wg[k][jj], k>=128 -> Ug[k-128][jj]
// ---------------------------------------------------------------------------
__global__ void pack_weights(const float* __restrict__ Wi, const float* __restrict__ Ui,
                             const float* __restrict__ Wf, const float* __restrict__ Uf,
                             const float* __restrict__ Wo, const float* __restrict__ Uo,
                             const float* __restrict__ Wc, const float* __restrict__ Uc,
                             unsigned short* __restrict__ Bhi, unsigned short* __restrict__ Blo) {
    int tid = blockIdx.x * blockDim.x + threadIdx.x;   // 0 .. 16383
    if (tid >= 8 * 32 * 64) return;
    int lane = tid & 63;
    int jg   = (tid >> 6) & 31;
    int kf   = tid >> 11;

    int j  = jg * 16 + (lane & 15);    // 0..511
    int g  = j >> 7;
    int jj = j & 127;
    const float* W = (g == 0) ? Wi : (g == 1) ? Wf : (g == 2) ? Wo : Wc;
    const float* U = (g == 0) ? Ui : (g == 1) ? Uf : (g == 2) ? Uo : Uc;

    int k0 = kf * 32 + ((lane >> 4) << 3);
    s16x8 h8, l8;
    #pragma unroll
    for (int e = 0; e < 8; ++e) {
        int k = k0 + e;
        float v = (k < 128) ? W[k * 128 + jj] : U[(k - 128) * 128 + jj];
        unsigned short h = f2bf(v);
        float r = v - bf2f(h);
        h8[e] = (short)h;
        l8[e] = (short)f2bf(r);
    }
    size_t off = (size_t)tid * 8;
    *reinterpret_cast<s16x8*>(Bhi + off) = h8;
    *reinterpret_cast<s16x8*>(Blo + off) = l8;
}

// ---------------------------------------------------------------------------
// Main fused kernel: per block, 64 rows x full N=512.
// 8 waves; wave w owns output h-columns [w*16, w*16+16) for ALL 4 gates ->
// elementwise LSTM epilogue entirely in registers.
// ---------------------------------------------------------------------------
__global__ __launch_bounds__(512, 2) void lstm_main(
        const float* __restrict__ x, const float* __restrict__ hprev,
        const float* __restrict__ cprev,
        const unsigned short* __restrict__ Bhi, const unsigned short* __restrict__ Blo,
        const float* __restrict__ bi, const float* __restrict__ bf_,
        const float* __restrict__ bo, const float* __restrict__ bc,
        float* __restrict__ hout, float* __restrict__ cout) {

    extern __shared__ unsigned short smem[];           // 64 KiB: a_hi[64*256], a_lo[64*256]
    unsigned short* a_hi = smem;
    unsigned short* a_lo = smem + BM * KDIM;
    char* a_hi_c = reinterpret_cast<char*>(a_hi);
    char* a_lo_c = reinterpret_cast<char*>(a_lo);

    const int t    = threadIdx.x;
    const int lane = t & 63;
    const int w    = t >> 6;
    const int row0 = blockIdx.x * BM;

    // ---- stage A = [x | h_prev] tile (64 x 256) as bf16 hi/lo, swizzled ----
    // float4 index f4 = s*512 + t: row = f4>>6, k0 = (f4&63)*4  (k<128 from x, else h_prev)
    #pragma unroll
    for (int s = 0; s < 8; ++s) {
        int f4  = s * 512 + t;
        int row = f4 >> 6;
        int k0  = (f4 & 63) * 4;
        const float* src = (k0 < 128)
            ? (x     + (size_t)(row0 + row) * 128 + k0)
            : (hprev + (size_t)(row0 + row) * 128 + (k0 - 128));
        f32x4 v = *reinterpret_cast<const f32x4*>(src);

        unsigned short h0 = f2bf(v.x), h1 = f2bf(v.y), h2 = f2bf(v.z), h3 = f2bf(v.w);
        unsigned short l0 = f2bf(v.x - bf2f(h0));
        unsigned short l1 = f2bf(v.y - bf2f(h1));
        unsigned short l2 = f2bf(v.z - bf2f(h2));
        unsigned short l3 = f2bf(v.w - bf2f(h3));

        uint2 hh, ll;
        hh.x = (unsigned)h0 | ((unsigned)h1 << 16);
        hh.y = (unsigned)h2 | ((unsigned)h3 << 16);
        ll.x = (unsigned)l0 | ((unsigned)l1 << 16);
        ll.y = (unsigned)l2 | ((unsigned)l3 << 16);

        int byte = (row * 512 + k0 * 2) ^ ((row & 7) << 4);   // XOR swizzle (G4)
        *reinterpret_cast<uint2*>(a_hi_c + byte) = hh;
        *reinterpret_cast<uint2*>(a_lo_c + byte) = ll;
    }
    __syncthreads();

    // ---- MFMA main loop: K = 256 = 8 kf-steps of 32 ----
    f32x4 acc[4][4];                                   // [m-frag][gate]
    #pragma unroll
    for (int m = 0; m < 4; ++m)
        #pragma unroll
        for (int g = 0; g < 4; ++g)
            acc[m][g] = (f32x4){0.f, 0.f, 0.f, 0.f};

    #pragma unroll
    for (int kf = 0; kf < 8; ++kf) {
        // A-fragments for 4 m-frags, hi and lo
        s16x8 af[4], al[4];
        #pragma unroll
        for (int m = 0; m < 4; ++m) {
            int row   = m * 16 + (lane & 15);
            int kbyte = kf * 64 + ((lane >> 4) << 4);
            int byte  = (row * 512 + kbyte) ^ ((row & 7) << 4);
            af[m] = *reinterpret_cast<const s16x8*>(a_hi_c + byte);
            al[m] = *reinterpret_cast<const s16x8*>(a_lo_c + byte);
        }
        // B-fragments per gate straight from L2-resident packed weights
        #pragma unroll
        for (int g = 0; g < 4; ++g) {
            size_t boff = ((size_t)((kf * 32 + g * 8 + w) * 64 + lane)) * 8;
            s16x8 bh = *reinterpret_cast<const s16x8*>(Bhi + boff);
            s16x8 bl = *reinterpret_cast<const s16x8*>(Blo + boff);
            #pragma unroll
            for (int m = 0; m < 4; ++m) {
                acc[m][g] = __builtin_amdgcn_mfma_f32_16x16x32_bf16(af[m], bh, acc[m][g], 0, 0, 0);
                acc[m][g] = __builtin_amdgcn_mfma_f32_16x16x32_bf16(af[m], bl, acc[m][g], 0, 0, 0);
                acc[m][g] = __builtin_amdgcn_mfma_f32_16x16x32_bf16(al[m], bh, acc[m][g], 0, 0, 0);
            }
        }
    }

    // ---- fused LSTM epilogue on accumulator registers ----
    // C/D layout (m89-verified): col = lane&15 (our j within 16), row = (lane>>4)*4 + reg
    const int j = w * 16 + (lane & 15);                // 0..127
    const float vbi = bi[j], vbf = bf_[j], vbo = bo[j], vbc = bc[j];

    #pragma unroll
    for (int m = 0; m < 4; ++m) {
        int rbase = row0 + m * 16 + ((lane >> 4) << 2);
        #pragma unroll
        for (int r = 0; r < 4; ++r) {
            size_t off = (size_t)(rbase + r) * 128 + j;
            float gi = acc[m][0][r] + vbi;
            float gf = acc[m][1][r] + vbf;
            float go = acc[m][2][r] + vbo;
            float gc = acc[m][3][r] + vbc;
            float iv = sigmoid_f(gi);
            float fv = sigmoid_f(gf);
            float ov = sigmoid_f(go);
            float cc = tanh_f(gc);
            float cp = cprev[off];
            float cn = fv * cp + iv * cc;
            float hn = ov * tanh_f(cn);
            hout[off] = hn;
            cout[off] = cn;
        }
    }
}

// ---------------------------------------------------------------------------
extern "C" void kernel_launch(void* const* d_in, const int* in_sizes, int n_in,
                              void* d_out, int out_size, void* d_ws, size_t ws_size,
                              hipStream_t stream) {
    const float* x  = (const float*)d_in[0];
    const float* hm = (const float*)d_in[1];
    const float* Wi = (const float*)d_in[2];
    const float* Ui = (const float*)d_in[3];
    const float* bi = (const float*)d_in[4];
    const float* Wf = (const float*)d_in[5];
    const float* Uf = (const float*)d_in[6];
    const float* bf = (const float*)d_in[7];
    const float* Wo = (const float*)d_in[8];
    const float* Uo = (const float*)d_in[9];
    const float* bo = (const float*)d_in[10];
    const float* Wc = (const float*)d_in[11];
    const float* Uc = (const float*)d_in[12];
    const float* bc = (const float*)d_in[13];

    const size_t BH = (size_t)NB * 128;
    const float* hprev = hm;
    const float* cprev = hm + BH;
    float* hout = (float*)d_out;
    float* cout = (float*)d_out + BH;

    unsigned short* Bhi = (unsigned short*)d_ws;              // 256*512 ushort = 256 KiB
    unsigned short* Blo = Bhi + (size_t)KDIM * NDIM;          // another 256 KiB

    pack_weights<<<64, 256, 0, stream>>>(Wi, Ui, Wf, Uf, Wo, Uo, Wc, Uc, Bhi, Blo);

    const int grid = NB / BM;                                  // 2048
    lstm_main<<<grid, 512, 2 * BM * KDIM * sizeof(unsigned short), stream>>>(
        x, hprev, cprev, Bhi, Blo, bi, bf, bo, bc, hout, cout);
}